// Round 1
// baseline (588.517 us; speedup 1.0000x reference)
//
#include <hip/hip_runtime.h>
#include <hip/hip_bf16.h>

// MultiHeadAttentionSelf: B=4, TQ=1024, TKV=2048, D=1024, H=16, DH=64
// Outputs (flat f32): out [4,1024,1024] @0, k_cache [4,2048,1024] @4194304,
//                     v_cache [4,2048,1024] @12582912.
// Strategy: bf16 MFMA (16x16x32) for all GEMMs + flash-style attention.
// Workspace layout (bytes):
//   x_bf    @0         8 MB   bf16 [4096,1024]
//   wqkv_bf @8388608   6 MB   bf16 [3072,1024]  (Wq;Wk;Wv rows)
//   wo_bf   @14680064  2 MB   bf16 [1024,1024]
//   biasqkv @16777216  12 KB  f32  [3072]       (bq;0;bv)
//   q_bf    @16789504  8 MB   bf16 [4096,1024]
//   k_bf    @25178112  16 MB  bf16 [4,2048,1024] (full K incl. cache)
//   vT_bf   @41955328  16 MB  bf16 [64,64,2048]  (per (b,h): [DH][TKV])
//   wv_bf   @58732544  8 MB   bf16 [4096,1024]
// total 67,121,152 bytes (~64 MB)

typedef __bf16 bf16_t;
typedef __attribute__((ext_vector_type(4))) float f32x4;
typedef __attribute__((ext_vector_type(8))) __bf16 bf16x8;
typedef __attribute__((ext_vector_type(4))) __bf16 bf16x4;

__device__ inline bf16x4 cvt4(float4 f) {
    bf16x4 o;
    o.x = (bf16_t)f.x; o.y = (bf16_t)f.y; o.z = (bf16_t)f.z; o.w = (bf16_t)f.w;
    return o;
}

// ---------------- prep kernels ----------------

__global__ void cast_f32_bf16_k(const float* __restrict__ src, bf16_t* __restrict__ dst, int n4) {
    int i = blockIdx.x * blockDim.x + threadIdx.x;
    if (i >= n4) return;
    float4 f = reinterpret_cast<const float4*>(src)[i];
    reinterpret_cast<bf16x4*>(dst)[i] = cvt4(f);
}

__global__ void build_wqkv_k(const float* __restrict__ Wq, const float* __restrict__ Wk,
                             const float* __restrict__ Wv, bf16_t* __restrict__ dst) {
    int i = blockIdx.x * blockDim.x + threadIdx.x;   // float4 index, 786432 total
    if (i >= 786432) return;
    int e0 = i * 4;
    int row = e0 >> 10;
    const float* src;
    if (row < 1024)       src = Wq + e0;
    else if (row < 2048)  src = Wk + (e0 - 1048576);
    else                  src = Wv + (e0 - 2097152);
    float4 f = *reinterpret_cast<const float4*>(src);
    reinterpret_cast<bf16x4*>(dst)[i] = cvt4(f);
}

__global__ void build_bias_k(const float* __restrict__ bq, const float* __restrict__ bv,
                             float* __restrict__ bias) {
    int i = blockIdx.x * blockDim.x + threadIdx.x;
    if (i >= 3072) return;
    float v;
    if (i < 1024)      v = bq[i];
    else if (i < 2048) v = 0.f;                 // key has no bias
    else               v = bv[i - 2048];
    bias[i] = v;
}

// copy old cache rows (first 1024 of each batch) f32->f32, optional bf16 shadow
__global__ void copy_old_k(const float* __restrict__ src, float* __restrict__ dstF,
                           bf16_t* __restrict__ dstB, int hasBf) {
    int i = blockIdx.x * blockDim.x + threadIdx.x;   // float4 index, 1048576 total
    if (i >= 1048576) return;
    int b = i >> 18;            // 262144 float4 per batch (rows 0..1023)
    int r = i & 262143;
    size_t off = (size_t)b * 2097152 + (size_t)r * 4;
    float4 f = *reinterpret_cast<const float4*>(src + off);
    *reinterpret_cast<float4*>(dstF + off) = f;
    if (hasBf) reinterpret_cast<bf16x4*>(dstB + off)[0] = cvt4(f);
}

// transpose V: vout f32 [4,2048,1024] -> vT bf16 [bh=64][dh=64][kv=2048]
__global__ __launch_bounds__(256) void transpose_v_k(const float* __restrict__ vout,
                                                     bf16_t* __restrict__ vT) {
    __shared__ bf16_t t[64][65];
    int blk = blockIdx.x;         // 2048 = kvt(32) * bh(64)
    int kvt = blk >> 6;
    int bh  = blk & 63;
    int b = bh >> 4, h = bh & 15;
    int kv0 = kvt * 64;
    int tid = threadIdx.x;
    int c = tid & 63, r0 = tid >> 6;
    #pragma unroll
    for (int rr = r0; rr < 64; rr += 4)
        t[rr][c] = (bf16_t)vout[((size_t)b * 2048 + kv0 + rr) * 1024 + h * 64 + c];
    __syncthreads();
    #pragma unroll
    for (int dd = r0; dd < 64; dd += 4)
        vT[((size_t)bh * 64 + dd) * 2048 + kv0 + c] = t[c][dd];
}

// ---------------- GEMM: C[M,N] = A[M,K] * Bw[N,K]^T + bias ----------------
// MODE 0: QKV epilogue (q->bf16 ws, k->f32 out + bf16 ws, v->f32 out)
// MODE 1: out = val -> f32 out0
template <int MODE>
__global__ __launch_bounds__(256) void gemm_bt_k(const bf16_t* __restrict__ A,
                                                 const bf16_t* __restrict__ Bw,
                                                 const float* __restrict__ bias,
                                                 bf16_t* __restrict__ q_bf,
                                                 float* __restrict__ kout,
                                                 bf16_t* __restrict__ k_bf,
                                                 float* __restrict__ vout,
                                                 float* __restrict__ out0) {
    const int K = 1024;
    int m0 = blockIdx.x * 128, n0 = blockIdx.y * 128;
    int tid = threadIdx.x;
    int lane = tid & 63, w = tid >> 6;
    int wr = w >> 1, wc = w & 1;
    int col16 = lane & 15, quad = lane >> 4;
    int mbase = m0 + wr * 64, nbase = n0 + wc * 64;

    f32x4 zero = {0.f, 0.f, 0.f, 0.f};
    f32x4 acc[4][4];
    #pragma unroll
    for (int mi = 0; mi < 4; mi++)
        #pragma unroll
        for (int ni = 0; ni < 4; ni++) acc[mi][ni] = zero;

    for (int k = 0; k < K; k += 32) {
        bf16x8 af[4], bfr[4];
        #pragma unroll
        for (int mi = 0; mi < 4; mi++)
            af[mi] = *reinterpret_cast<const bf16x8*>(
                A + (size_t)(mbase + mi * 16 + col16) * K + k + quad * 8);
        #pragma unroll
        for (int ni = 0; ni < 4; ni++)
            bfr[ni] = *reinterpret_cast<const bf16x8*>(
                Bw + (size_t)(nbase + ni * 16 + col16) * K + k + quad * 8);
        #pragma unroll
        for (int mi = 0; mi < 4; mi++)
            #pragma unroll
            for (int ni = 0; ni < 4; ni++)
                acc[mi][ni] = __builtin_amdgcn_mfma_f32_16x16x32_bf16(
                    af[mi], bfr[ni], acc[mi][ni], 0, 0, 0);
    }

    #pragma unroll
    for (int mi = 0; mi < 4; mi++) {
        #pragma unroll
        for (int ni = 0; ni < 4; ni++) {
            int gm_base = mbase + mi * 16 + quad * 4;
            int gn = nbase + ni * 16 + col16;
            float bia = bias[gn];
            #pragma unroll
            for (int r = 0; r < 4; r++) {
                int gm = gm_base + r;
                float v = acc[mi][ni][r] + bia;
                if (MODE == 0) {
                    if (gn < 1024) {
                        q_bf[(size_t)gm * 1024 + gn] = (bf16_t)v;
                    } else if (gn < 2048) {
                        int n2 = gn - 1024;
                        int b = gm >> 10, t = gm & 1023;
                        size_t off = ((size_t)b * 2048 + 1024 + t) * 1024 + n2;
                        kout[off] = v;
                        k_bf[off] = (bf16_t)v;
                    } else {
                        int n2 = gn - 2048;
                        int b = gm >> 10, t = gm & 1023;
                        vout[((size_t)b * 2048 + 1024 + t) * 1024 + n2] = v;
                    }
                } else {
                    out0[(size_t)gm * 1024 + gn] = v;
                }
            }
        }
    }
}

// ---------------- flash attention ----------------
// grid: 1024 blocks = qt(16) major * bh(64) minor; block = 4 waves, wave = 16 q rows
__global__ __launch_bounds__(256) void attn_k(const bf16_t* __restrict__ qbf,
                                              const bf16_t* __restrict__ kbf,
                                              const bf16_t* __restrict__ vT,
                                              const float* __restrict__ mask,
                                              bf16_t* __restrict__ wv) {
    __shared__ __align__(16) bf16_t plds[4][16][64];
    int blk = blockIdx.x;
    int qt = blk >> 6;          // 0..15
    int bh = blk & 63;
    int b = bh >> 4, h = bh & 15;
    int tid = threadIdx.x, w = tid >> 6, lane = tid & 63;
    int col16 = lane & 15, quad = lane >> 4;
    int qr0 = qt * 64 + w * 16;

    // Q fragments: A[m=lane&15][k=quad*8+j], DH=64 -> 2 k-steps
    const bf16_t* qrow = qbf + ((size_t)b * 1024 + qr0 + col16) * 1024 + h * 64;
    bf16x8 aq0 = *reinterpret_cast<const bf16x8*>(qrow + quad * 8);
    bf16x8 aq1 = *reinterpret_cast<const bf16x8*>(qrow + 32 + quad * 8);

    f32x4 zero = {0.f, 0.f, 0.f, 0.f};
    float mrow[4], lrow[4];
    f32x4 oacc[4];
    #pragma unroll
    for (int r = 0; r < 4; r++) { mrow[r] = -3.0e38f; lrow[r] = 0.f; }
    #pragma unroll
    for (int dt = 0; dt < 4; dt++) oacc[dt] = zero;

    for (int kv0 = 0; kv0 < 2048; kv0 += 64) {
        // ---- S = Q K^T (16 x 64) ----
        f32x4 s[4];
        #pragma unroll
        for (int nt = 0; nt < 4; nt++) {
            s[nt] = zero;
            const bf16_t* krow =
                kbf + ((size_t)b * 2048 + kv0 + nt * 16 + col16) * 1024 + h * 64;
            s[nt] = __builtin_amdgcn_mfma_f32_16x16x32_bf16(
                aq0, *reinterpret_cast<const bf16x8*>(krow + quad * 8), s[nt], 0, 0, 0);
            s[nt] = __builtin_amdgcn_mfma_f32_16x16x32_bf16(
                aq1, *reinterpret_cast<const bf16x8*>(krow + 32 + quad * 8), s[nt], 0, 0, 0);
        }
        // ---- scale + mask; row = quad*4+r, col = kv0+nt*16+col16 ----
        float sv[4][4];
        #pragma unroll
        for (int nt = 0; nt < 4; nt++)
            #pragma unroll
            for (int r = 0; r < 4; r++)
                sv[nt][r] = s[nt][r] * 0.125f +
                            mask[(size_t)(qr0 + quad * 4 + r) * 2048 + kv0 + nt * 16 + col16];
        // ---- online softmax: rowwise max over this kv tile ----
        float cm[4];
        #pragma unroll
        for (int r = 0; r < 4; r++)
            cm[r] = fmaxf(fmaxf(sv[0][r], sv[1][r]), fmaxf(sv[2][r], sv[3][r]));
        #pragma unroll
        for (int d = 1; d < 16; d <<= 1)
            #pragma unroll
            for (int r = 0; r < 4; r++) cm[r] = fmaxf(cm[r], __shfl_xor(cm[r], d));
        float alpha[4], nm[4];
        #pragma unroll
        for (int r = 0; r < 4; r++) {
            nm[r] = fmaxf(mrow[r], cm[r]);
            alpha[r] = __expf(mrow[r] - nm[r]);
            mrow[r] = nm[r];
        }
        float ls[4] = {0.f, 0.f, 0.f, 0.f};
        #pragma unroll
        for (int nt = 0; nt < 4; nt++)
            #pragma unroll
            for (int r = 0; r < 4; r++) {
                float p = __expf(sv[nt][r] - nm[r]);
                ls[r] += p;
                plds[w][quad * 4 + r][nt * 16 + col16] = (bf16_t)p;
            }
        #pragma unroll
        for (int d = 1; d < 16; d <<= 1)
            #pragma unroll
            for (int r = 0; r < 4; r++) ls[r] += __shfl_xor(ls[r], d);
        #pragma unroll
        for (int r = 0; r < 4; r++) lrow[r] = lrow[r] * alpha[r] + ls[r];
        #pragma unroll
        for (int dt = 0; dt < 4; dt++)
            #pragma unroll
            for (int r = 0; r < 4; r++) oacc[dt][r] *= alpha[r];
        __syncthreads();   // P tile written -> readable as A fragments
        // ---- O += P V : A = P [16 x 64], B = vT (K-contiguous) ----
        bf16x8 pf0 = *reinterpret_cast<const bf16x8*>(&plds[w][col16][quad * 8]);
        bf16x8 pf1 = *reinterpret_cast<const bf16x8*>(&plds[w][col16][32 + quad * 8]);
        #pragma unroll
        for (int dt = 0; dt < 4; dt++) {
            const bf16_t* vrow = vT + ((size_t)bh * 64 + dt * 16 + col16) * 2048 + kv0;
            oacc[dt] = __builtin_amdgcn_mfma_f32_16x16x32_bf16(
                pf0, *reinterpret_cast<const bf16x8*>(vrow + quad * 8), oacc[dt], 0, 0, 0);
            oacc[dt] = __builtin_amdgcn_mfma_f32_16x16x32_bf16(
                pf1, *reinterpret_cast<const bf16x8*>(vrow + 32 + quad * 8), oacc[dt], 0, 0, 0);
        }
        __syncthreads();
    }
    float inv[4];
    #pragma unroll
    for (int r = 0; r < 4; r++) inv[r] = 1.f / lrow[r];
    #pragma unroll
    for (int dt = 0; dt < 4; dt++)
        #pragma unroll
        for (int r = 0; r < 4; r++)
            wv[((size_t)b * 1024 + qr0 + quad * 4 + r) * 1024 + h * 64 + dt * 16 + col16] =
                (bf16_t)(oacc[dt][r] * inv[r]);
}

// ---------------- launcher ----------------

extern "C" void kernel_launch(void* const* d_in, const int* in_sizes, int n_in,
                              void* d_out, int out_size, void* d_ws, size_t ws_size,
                              hipStream_t stream) {
    const float* x    = (const float*)d_in[0];
    const float* kc   = (const float*)d_in[1];
    const float* vc   = (const float*)d_in[2];
    const float* mask = (const float*)d_in[3];
    const float* Wq   = (const float*)d_in[4];
    const float* bq   = (const float*)d_in[5];
    const float* Wk   = (const float*)d_in[6];
    const float* Wv   = (const float*)d_in[7];
    const float* bv   = (const float*)d_in[8];
    const float* Wo   = (const float*)d_in[9];
    const float* bo   = (const float*)d_in[10];

    float* out0 = (float*)d_out;
    float* kout = out0 + 4194304;
    float* vout = out0 + 12582912;

    char* ws = (char*)d_ws;
    bf16_t* x_bf     = (bf16_t*)(ws);
    bf16_t* wqkv_bf  = (bf16_t*)(ws + 8388608);
    bf16_t* wo_bf    = (bf16_t*)(ws + 14680064);
    float*  bias_qkv = (float*)(ws + 16777216);
    bf16_t* q_bf     = (bf16_t*)(ws + 16789504);
    bf16_t* k_bf     = (bf16_t*)(ws + 25178112);
    bf16_t* vT_bf    = (bf16_t*)(ws + 41955328);
    bf16_t* wv_bf    = (bf16_t*)(ws + 58732544);

    cast_f32_bf16_k<<<4096, 256, 0, stream>>>(x, x_bf, 1048576);
    build_wqkv_k<<<3072, 256, 0, stream>>>(Wq, Wk, Wv, wqkv_bf);
    cast_f32_bf16_k<<<1024, 256, 0, stream>>>(Wo, wo_bf, 262144);
    build_bias_k<<<12, 256, 0, stream>>>(bq, bv, bias_qkv);
    copy_old_k<<<4096, 256, 0, stream>>>(kc, kout, k_bf, 1);
    copy_old_k<<<4096, 256, 0, stream>>>(vc, vout, (bf16_t*)nullptr, 0);
    gemm_bt_k<0><<<dim3(32, 24), 256, 0, stream>>>(x_bf, wqkv_bf, bias_qkv,
                                                   q_bf, kout, k_bf, vout, nullptr);
    transpose_v_k<<<2048, 256, 0, stream>>>(vout, vT_bf);
    attn_k<<<1024, 256, 0, stream>>>(q_bf, k_bf, vT_bf, mask, wv_bf);
    gemm_bt_k<1><<<dim3(32, 8), 256, 0, stream>>>(wv_bf, wo_bf, bo,
                                                  nullptr, nullptr, nullptr, nullptr, out0);
}